// Round 3
// baseline (841.203 us; speedup 1.0000x reference)
//
#include <hip/hip_runtime.h>

#define NTOK 49
#define HEADS 6
#define CDIM 192
#define NWIN 4096

typedef unsigned short u16;
typedef unsigned int u32;
typedef unsigned long long u64;
typedef __attribute__((ext_vector_type(8))) __bf16 bf16x8;
typedef __attribute__((ext_vector_type(4))) float floatx4;
typedef __attribute__((ext_vector_type(4))) u32 u32x4;

struct __attribute__((aligned(4))) F4 { float f[4]; };

// LDS regions (bytes). Total 76800 <= 81920 -> 2 blocks/CU.
#define R1_OFF 0        // X stage [64][200] u16 (25600) ; then Vt [192][64] u16 rot-swizzled (24576)
#define R2_OFF 25600    // Q [64][200] u16 ; then AOB [4 nt][6 h][64 lane][8] u16 (24576)
#define R3_OFF 51200    // K [64][200] u16
#define LDS_BYTES 76800

__device__ __forceinline__ u16 f2bf(float f) {
  union { float f; u32 u; } v; v.f = f;
  u32 u = v.u;
  u = (u + 0x7FFFu + ((u >> 16) & 1u)) >> 16;
  return (u16)u;
}
__device__ __forceinline__ void st4bf(u16* p, float a, float b, float c, float d) {
  u64 t = (u64)f2bf(a) | ((u64)f2bf(b) << 16) | ((u64)f2bf(c) << 32) | ((u64)f2bf(d) << 48);
  *(u64*)p = t;
}
__device__ __forceinline__ float bf2f(u16 u) {
  union { u32 u; float f; } v; v.u = ((u32)u) << 16;
  return v.f;
}
// software RNE pack of two f32 -> 2x bf16 in one u32 (replaces v_cvt_pk_bf16_f32 asm,
// which produced NaN-pattern garbage in R2 — suspected operand-semantics mismatch)
__device__ __forceinline__ u32 pack2bf(float lo, float hi) {
  return (u32)f2bf(lo) | ((u32)f2bf(hi) << 16);
}
__device__ __forceinline__ bf16x8 frag_from_words(u32 a, u32 b, u32 c, u32 d) {
  u32x4 t = {a, b, c, d};
  return __builtin_bit_cast(bf16x8, t);
}

__global__ __launch_bounds__(256)
void wprep(const float* __restrict__ Wq, const float* __restrict__ Wk,
           const float* __restrict__ Wv, const float* __restrict__ Wp,
           const float* __restrict__ rpb, const int* __restrict__ rel,
           u16* __restrict__ w_bf, float* __restrict__ bias) {
  const int tid = blockIdx.x * blockDim.x + threadIdx.x;
  const int stride = gridDim.x * blockDim.x;
  for (int i = tid; i < 4 * CDIM * CDIM; i += stride) {
    const int p = i / (CDIM * CDIM), e = i % (CDIM * CDIM);
    float v = (p == 0) ? Wq[e] : (p == 1) ? Wk[e] : (p == 2) ? Wv[e] : Wp[e];
    w_bf[i] = f2bf(v);
  }
  for (int i = tid; i < HEADS * NTOK * NTOK; i += stride) {
    const int h = i / (NTOK * NTOK), nm = i % (NTOK * NTOK);
    bias[i] = rpb[rel[nm] * HEADS + h];
  }
}

__global__ __launch_bounds__(512, 4)
void wattn_main(const float* __restrict__ x, const float* __restrict__ mask,
                const float* __restrict__ d_l, const float* __restrict__ temp,
                const u16* __restrict__ w_bf, const float* __restrict__ bias,
                float* __restrict__ out) {
  extern __shared__ __align__(16) char smem[];
  u16* Xs  = (u16*)(smem + R1_OFF);
  u16* Vt  = (u16*)(smem + R1_OFF);
  u16* Qn  = (u16*)(smem + R2_OFF);
  u16* AOB = (u16*)(smem + R2_OFF);
  u16* Kn  = (u16*)(smem + R3_OFF);

  const int b = blockIdx.x;
  const int tid = threadIdx.x;
  const int wave = tid >> 6;
  const int lane = tid & 63;
  const int g = lane >> 4;
  const int nl = lane & 15;

  // ---- phase 0: stage x -> bf16 LDS [64][200], zero pad rows 49..63
  {
    const float* xb = x + (size_t)b * (NTOK * CDIM);
    for (int i = tid; i < NTOK * 48; i += 512) {
      const int n = i / 48;
      const int c = (i - n * 48) * 4;
      const float4 v = *(const float4*)(xb + n * CDIM + c);
      st4bf(Xs + n * 200 + c, v.x, v.y, v.z, v.w);
    }
    for (int i = tid; i < 15 * 48; i += 512) {
      const int n = NTOK + i / 48;
      const int c = (i % 48) * 4;
      *(u64*)(Xs + n * 200 + c) = 0ull;
    }
  }
  __syncthreads();

  // ---- phase 1a: per-wave xf fragments for this wave's token half
  const int nthalf = wave & 1;
  const int wg = wave >> 1;
  bf16x8 xf[2][6];
#pragma unroll
  for (int nt2 = 0; nt2 < 2; ++nt2)
#pragma unroll
    for (int k = 0; k < 6; ++k)
      xf[nt2][k] = *(const bf16x8*)(Xs + (nthalf * 32 + nt2 * 16 + nl) * 200 + k * 32 + g * 8);
  __syncthreads();  // R1 about to be overwritten by Vt

  // ---- phase 1b: QKV. tasks (p,o): 36 over 4 wave-groups (9 each), nt-half per wave parity
  for (int t = wg; t < 36; t += 4) {
    const int p = t / 12, o = t % 12;
    const u16* wb = w_bf + p * (CDIM * CDIM) + (o * 16 + nl) * CDIM + g * 8;
    bf16x8 wf[6];
#pragma unroll
    for (int k = 0; k < 6; ++k) wf[k] = *(const bf16x8*)(wb + k * 32);
    floatx4 acc[2];
    acc[0] = (floatx4){0.f, 0.f, 0.f, 0.f};
    acc[1] = (floatx4){0.f, 0.f, 0.f, 0.f};
    if (p < 2) {
#pragma unroll
      for (int k = 0; k < 6; ++k)
#pragma unroll
        for (int nt2 = 0; nt2 < 2; ++nt2)
          acc[nt2] = __builtin_amdgcn_mfma_f32_16x16x32_bf16(wf[k], xf[nt2][k], acc[nt2], 0, 0, 0);
      u16* dst = (p == 0 ? Qn : Kn);
#pragma unroll
      for (int nt2 = 0; nt2 < 2; ++nt2)
        st4bf(dst + (nthalf * 32 + nt2 * 16 + nl) * 200 + o * 16 + g * 4,
              acc[nt2][0], acc[nt2][1], acc[nt2][2], acc[nt2][3]);
    } else {
#pragma unroll
      for (int k = 0; k < 6; ++k)
#pragma unroll
        for (int nt2 = 0; nt2 < 2; ++nt2)
          acc[nt2] = __builtin_amdgcn_mfma_f32_16x16x32_bf16(xf[nt2][k], wf[k], acc[nt2], 0, 0, 0);
      const int row = o * 16 + nl;
#pragma unroll
      for (int nt2 = 0; nt2 < 2; ++nt2) {
        const int col = nthalf * 32 + nt2 * 16 + g * 4;
        const int colS = (col + ((nl & 3) << 4)) & 63;  // rotation swizzle vs stride-64 banks
        st4bf(Vt + row * 64 + colS, acc[nt2][0], acc[nt2][1], acc[nt2][2], acc[nt2][3]);
      }
    }
  }
  __syncthreads();

  // ---- phase 2: l2-normalize Q,K rows (4 lanes per (tensor,head,token))
  {
    const int sub = tid & 3;
    for (int ru = tid >> 2; ru < 2 * HEADS * NTOK; ru += 128) {
      const int t = ru / (HEADS * NTOK);
      const int rem = ru - t * (HEADS * NTOK);
      const int h = rem / NTOK, n = rem - h * NTOK;
      u16* base = (t == 0 ? Qn : Kn) + n * 200 + h * 32 + sub * 8;
      u64 lo = *(u64*)base;
      u64 hi = *(u64*)(base + 4);
      float f[8];
#pragma unroll
      for (int e = 0; e < 4; ++e) f[e] = bf2f((u16)(lo >> (16 * e)));
#pragma unroll
      for (int e = 0; e < 4; ++e) f[4 + e] = bf2f((u16)(hi >> (16 * e)));
      float ss = 0.f;
#pragma unroll
      for (int e = 0; e < 8; ++e) ss += f[e] * f[e];
      ss += __shfl_xor(ss, 1);
      ss += __shfl_xor(ss, 2);
      const float inv = 1.0f / fmaxf(sqrtf(ss), 1e-12f);
      st4bf(base, f[0] * inv, f[1] * inv, f[2] * inv, f[3] * inv);
      st4bf(base + 4, f[4] * inv, f[5] * inv, f[6] * inv, f[7] * inv);
    }
  }
  __syncthreads();

  // ---- phase 3a: S^T = K*Q^T, softmax, P -> in-register B-fragments
  const float dl = d_l[b];
  const int wmask = b & (NWIN - 1);
  const int srcA = nl + ((lane & 16) << 1);  // nl + 32*(g&1)
  const int srcB = srcA + 16;
  const bool hi = (g >> 1) != 0;
  u32 pf[3][2][4];  // [task][ks][word]
#pragma unroll
  for (int i = 0; i < 3; ++i) {
    const int t = wave + 8 * i;
    const int h = t >> 2, nt = t & 3;
    const int n = nt * 16 + nl;
    const int ncl = n < NTOK ? n : NTOK - 1;
    const float tdl = temp[h] * dl;
    const bf16x8 qf = *(const bf16x8*)(Qn + n * 200 + h * 32 + g * 8);
    floatx4 sacc[4];
#pragma unroll
    for (int rt = 0; rt < 4; ++rt) {
      const bf16x8 kf = *(const bf16x8*)(Kn + (rt * 16 + nl) * 200 + h * 32 + g * 8);
      sacc[rt] = __builtin_amdgcn_mfma_f32_16x16x32_bf16(kf, qf, (floatx4){0.f, 0.f, 0.f, 0.f}, 0, 0, 0);
    }
    const float* brow = bias + (h * NTOK + ncl) * NTOK;
    const float* mrow = mask + ((size_t)wmask * NTOK + ncl) * NTOK;
    float L[4][4];
    float pmax = -1e30f;
#pragma unroll
    for (int rt = 0; rt < 3; ++rt) {
      const F4 b4 = *(const F4*)(brow + rt * 16 + g * 4);
      const F4 m4 = *(const F4*)(mrow + rt * 16 + g * 4);
#pragma unroll
      for (int r = 0; r < 4; ++r) {
        const float lv = fmaf(sacc[rt][r], tdl, (b4.f[r] + m4.f[r]) * dl);
        L[rt][r] = lv;
        pmax = fmaxf(pmax, lv);
      }
    }
    {  // rt=3: only m=48 is real (lane g==0, r==0)
      const float lv48 = fmaf(sacc[3][0], tdl, (brow[48] + mrow[48]) * dl);
#pragma unroll
      for (int r = 0; r < 4; ++r) L[3][r] = -1e30f;
      if (g == 0) { L[3][0] = lv48; pmax = fmaxf(pmax, lv48); }
    }
    pmax = fmaxf(pmax, __shfl_xor(pmax, 16));
    pmax = fmaxf(pmax, __shfl_xor(pmax, 32));
    float psum = 0.f;
#pragma unroll
    for (int rt = 0; rt < 4; ++rt)
#pragma unroll
      for (int r = 0; r < 4; ++r) {
        const float e = __expf(L[rt][r] - pmax);
        L[rt][r] = e;
        psum += e;
      }
    psum += __shfl_xor(psum, 16);
    psum += __shfl_xor(psum, 32);
    const float rinv = 1.0f / psum;
    u32 pk[4][2];
#pragma unroll
    for (int rt = 0; rt < 4; ++rt)
#pragma unroll
      for (int w2 = 0; w2 < 2; ++w2)
        pk[rt][w2] = pack2bf(L[rt][2 * w2] * rinv, L[rt][2 * w2 + 1] * rinv);
    // cross-g exchange into B-fragment layout: elem j = P[32ks+8g+j][nl]
#pragma unroll
    for (int ks = 0; ks < 2; ++ks) {
      const u32 a0 = __shfl((int)pk[2 * ks][0], srcA), b0 = __shfl((int)pk[2 * ks + 1][0], srcA);
      const u32 a1 = __shfl((int)pk[2 * ks][1], srcA), b1 = __shfl((int)pk[2 * ks + 1][1], srcA);
      const u32 a2 = __shfl((int)pk[2 * ks][0], srcB), b2 = __shfl((int)pk[2 * ks + 1][0], srcB);
      const u32 a3 = __shfl((int)pk[2 * ks][1], srcB), b3 = __shfl((int)pk[2 * ks + 1][1], srcB);
      pf[i][ks][0] = hi ? b0 : a0;
      pf[i][ks][1] = hi ? b1 : a1;
      pf[i][ks][2] = hi ? b2 : a2;
      pf[i][ks][3] = hi ? b3 : a3;
    }
  }
  __syncthreads();  // Q region about to become AOB

  // ---- phase 3b: O^T = Vt*P per task, pack into phase-4 A-fragments in AOB
#pragma unroll
  for (int i = 0; i < 3; ++i) {
    const int t = wave + 8 * i;
    const int h = t >> 2, nt = t & 3;
    floatx4 oacc[2];
    oacc[0] = (floatx4){0.f, 0.f, 0.f, 0.f};
    oacc[1] = (floatx4){0.f, 0.f, 0.f, 0.f};
#pragma unroll
    for (int ks = 0; ks < 2; ++ks) {
      const bf16x8 pfr = frag_from_words(pf[i][ks][0], pf[i][ks][1], pf[i][ks][2], pf[i][ks][3]);
#pragma unroll
      for (int dt = 0; dt < 2; ++dt) {
        const int row = h * 32 + dt * 16 + nl;
        const int colS = (ks * 32 + g * 8 + ((nl & 3) << 4)) & 63;
        const bf16x8 vf = *(const bf16x8*)(Vt + row * 64 + colS);
        oacc[dt] = __builtin_amdgcn_mfma_f32_16x16x32_bf16(vf, pfr, oacc[dt], 0, 0, 0);
      }
    }
    u32 pka[2][2];
#pragma unroll
    for (int dt = 0; dt < 2; ++dt)
#pragma unroll
      for (int w2 = 0; w2 < 2; ++w2)
        pka[dt][w2] = pack2bf(oacc[dt][2 * w2], oacc[dt][2 * w2 + 1]);
    const u32 a0 = __shfl((int)pka[0][0], srcA), b0 = __shfl((int)pka[1][0], srcA);
    const u32 a1 = __shfl((int)pka[0][1], srcA), b1 = __shfl((int)pka[1][1], srcA);
    const u32 a2 = __shfl((int)pka[0][0], srcB), b2 = __shfl((int)pka[1][0], srcB);
    const u32 a3 = __shfl((int)pka[0][1], srcB), b3 = __shfl((int)pka[1][1], srcB);
    u32x4 frag;
    frag[0] = hi ? b0 : a0;
    frag[1] = hi ? b1 : a1;
    frag[2] = hi ? b2 : a2;
    frag[3] = hi ? b3 : a3;
    *(u32x4*)(AOB + ((size_t)(nt * 6 + h) * 64 + lane) * 8) = frag;
  }
  __syncthreads();

  // ---- phase 4: out = AO @ Wp^T, tasks (o,nt): 48 over 8 waves (6 each)
  {
    float* outb = out + (size_t)b * (NTOK * CDIM);
    const u16* wpb = w_bf + 3 * (CDIM * CDIM);
    for (int t = wave; t < 48; t += 8) {
      const int o = t >> 2, nt = t & 3;
      bf16x8 af[6], wfp[6];
#pragma unroll
      for (int h = 0; h < 6; ++h)
        af[h] = *(const bf16x8*)(AOB + ((nt * 6 + h) * 64 + lane) * 8);
#pragma unroll
      for (int ks = 0; ks < 6; ++ks)
        wfp[ks] = *(const bf16x8*)(wpb + (o * 16 + nl) * CDIM + ks * 32 + g * 8);
      floatx4 acc = (floatx4){0.f, 0.f, 0.f, 0.f};
#pragma unroll
      for (int ks = 0; ks < 6; ++ks)
        acc = __builtin_amdgcn_mfma_f32_16x16x32_bf16(af[ks], wfp[ks], acc, 0, 0, 0);
#pragma unroll
      for (int r = 0; r < 4; ++r) {
        const int tok = nt * 16 + g * 4 + r;
        if (tok < NTOK) outb[tok * CDIM + o * 16 + nl] = acc[r];
      }
    }
  }
}

extern "C" void kernel_launch(void* const* d_in, const int* in_sizes, int n_in,
                              void* d_out, int out_size, void* d_ws, size_t ws_size,
                              hipStream_t stream) {
  const float* x    = (const float*)d_in[0];
  const float* mask = (const float*)d_in[1];
  const float* dl   = (const float*)d_in[2];
  const float* Wq   = (const float*)d_in[3];
  const float* Wk   = (const float*)d_in[4];
  const float* Wv   = (const float*)d_in[5];
  const float* Wp   = (const float*)d_in[6];
  const float* temp = (const float*)d_in[7];
  const float* rpb  = (const float*)d_in[8];
  const int*   rel  = (const int*)d_in[9];

  u16* w_bf = (u16*)d_ws;
  float* bias = (float*)((char*)d_ws + (size_t)4 * CDIM * CDIM * sizeof(u16));
  float* o = (float*)d_out;

  (void)hipFuncSetAttribute((const void*)wattn_main,
                            hipFuncAttributeMaxDynamicSharedMemorySize, LDS_BYTES);

  wprep<<<256, 256, 0, stream>>>(Wq, Wk, Wv, Wp, rpb, rel, w_bf, bias);
  wattn_main<<<8192, 512, LDS_BYTES, stream>>>(x, mask, dl, temp, w_bf, bias, o);
}